// Round 3
// baseline (240.598 us; speedup 1.0000x reference)
//
#include <hip/hip_runtime.h>

// input_tensor: (32, 64, 64, 64) fp32  -- d_in[0]
// pool_input:   (32, 128, 128, 64) fp32 -- d_in[1]
// out:          (32, 128, 128, 64) fp32
// POOL == STRIDES == (2,2): non-overlapping windows ->
//   out[b,h,w,c] = (pool[b,h,w,c] == window max) ? input[b,h/2,w/2,c] : 0
//
// R2: 4 windows per thread (batch quarters b, b+8, b+16, b+24), 20
// independent loads issued up front (~2x R1 MLP), non-temporal everywhere.

#define BB 32
#define HH 128
#define WW 128
#define CC 64
#define HO 64
#define WO 64
#define C4 (CC / 4)          // 16 float4 per (b,h,w)
#define WC4 (WW * C4)        // 2048 float4 per pool row
#define QB 8                                  // batches per quarter
#define QN (QB * HO * WO * C4)                // 524,288 threads
#define IN_Q (QB * HO * WO * C4)              // input float4 per quarter
#define POOL_Q (QB * HH * WW * C4)            // pool float4 per quarter

typedef float v4 __attribute__((ext_vector_type(4)));

__device__ __forceinline__ v4 vmax4(v4 a, v4 b) {
    v4 r;
    r.x = fmaxf(a.x, b.x); r.y = fmaxf(a.y, b.y);
    r.z = fmaxf(a.z, b.z); r.w = fmaxf(a.w, b.w);
    return r;
}

__device__ __forceinline__ v4 vsel(v4 p, v4 m, v4 v) {
    v4 r;
    r.x = (p.x == m.x) ? v.x : 0.0f;
    r.y = (p.y == m.y) ? v.y : 0.0f;
    r.z = (p.z == m.z) ? v.z : 0.0f;
    r.w = (p.w == m.w) ? v.w : 0.0f;
    return r;
}

__global__ __launch_bounds__(256) void unpool2d_kernel(
    const v4* __restrict__ input,  // (B,HO,WO,C4)
    const v4* __restrict__ pool,   // (B,H,W,C4)
    v4* __restrict__ out)          // (B,H,W,C4)
{
    const int t = blockIdx.x * blockDim.x + threadIdx.x;   // [0, QN)
    const int c4 = t & (C4 - 1);
    const int j  = (t >> 4) & (WO - 1);
    const int i  = (t >> 10) & (HO - 1);
    const int b  = t >> 16;                                 // 0..7

    const int base0 = ((b * HH + 2 * i) * WW + 2 * j) * C4 + c4;
    const int base1 = base0 + POOL_Q;
    const int base2 = base0 + 2 * POOL_Q;
    const int base3 = base0 + 3 * POOL_Q;

    // 20 independent loads, all issued before any use.
    const v4 a00 = __builtin_nontemporal_load(&pool[base0]);
    const v4 a01 = __builtin_nontemporal_load(&pool[base0 + C4]);
    const v4 a10 = __builtin_nontemporal_load(&pool[base0 + WC4]);
    const v4 a11 = __builtin_nontemporal_load(&pool[base0 + WC4 + C4]);
    const v4 b00 = __builtin_nontemporal_load(&pool[base1]);
    const v4 b01 = __builtin_nontemporal_load(&pool[base1 + C4]);
    const v4 b10 = __builtin_nontemporal_load(&pool[base1 + WC4]);
    const v4 b11 = __builtin_nontemporal_load(&pool[base1 + WC4 + C4]);
    const v4 c00 = __builtin_nontemporal_load(&pool[base2]);
    const v4 c01 = __builtin_nontemporal_load(&pool[base2 + C4]);
    const v4 c10 = __builtin_nontemporal_load(&pool[base2 + WC4]);
    const v4 c11 = __builtin_nontemporal_load(&pool[base2 + WC4 + C4]);
    const v4 d00 = __builtin_nontemporal_load(&pool[base3]);
    const v4 d01 = __builtin_nontemporal_load(&pool[base3 + C4]);
    const v4 d10 = __builtin_nontemporal_load(&pool[base3 + WC4]);
    const v4 d11 = __builtin_nontemporal_load(&pool[base3 + WC4 + C4]);
    const v4 vA  = __builtin_nontemporal_load(&input[t]);
    const v4 vB  = __builtin_nontemporal_load(&input[t + IN_Q]);
    const v4 vC  = __builtin_nontemporal_load(&input[t + 2 * IN_Q]);
    const v4 vD  = __builtin_nontemporal_load(&input[t + 3 * IN_Q]);

    const v4 mA = vmax4(vmax4(a00, a01), vmax4(a10, a11));
    const v4 mB = vmax4(vmax4(b00, b01), vmax4(b10, b11));
    const v4 mC = vmax4(vmax4(c00, c01), vmax4(c10, c11));
    const v4 mD = vmax4(vmax4(d00, d01), vmax4(d10, d11));

    __builtin_nontemporal_store(vsel(a00, mA, vA), &out[base0]);
    __builtin_nontemporal_store(vsel(a01, mA, vA), &out[base0 + C4]);
    __builtin_nontemporal_store(vsel(a10, mA, vA), &out[base0 + WC4]);
    __builtin_nontemporal_store(vsel(a11, mA, vA), &out[base0 + WC4 + C4]);
    __builtin_nontemporal_store(vsel(b00, mB, vB), &out[base1]);
    __builtin_nontemporal_store(vsel(b01, mB, vB), &out[base1 + C4]);
    __builtin_nontemporal_store(vsel(b10, mB, vB), &out[base1 + WC4]);
    __builtin_nontemporal_store(vsel(b11, mB, vB), &out[base1 + WC4 + C4]);
    __builtin_nontemporal_store(vsel(c00, mC, vC), &out[base2]);
    __builtin_nontemporal_store(vsel(c01, mC, vC), &out[base2 + C4]);
    __builtin_nontemporal_store(vsel(c10, mC, vC), &out[base2 + WC4]);
    __builtin_nontemporal_store(vsel(c11, mC, vC), &out[base2 + WC4 + C4]);
    __builtin_nontemporal_store(vsel(d00, mD, vD), &out[base3]);
    __builtin_nontemporal_store(vsel(d01, mD, vD), &out[base3 + C4]);
    __builtin_nontemporal_store(vsel(d10, mD, vD), &out[base3 + WC4]);
    __builtin_nontemporal_store(vsel(d11, mD, vD), &out[base3 + WC4 + C4]);
}

extern "C" void kernel_launch(void* const* d_in, const int* in_sizes, int n_in,
                              void* d_out, int out_size, void* d_ws, size_t ws_size,
                              hipStream_t stream) {
    const v4* input = (const v4*)d_in[0];
    const v4* pool  = (const v4*)d_in[1];
    v4* out = (v4*)d_out;

    const int block = 256;
    const int grid = QN / block;   // 2048 blocks
    unpool2d_kernel<<<grid, block, 0, stream>>>(input, pool, out);
}

// Round 4
// 238.258 us; speedup vs baseline: 1.0098x; 1.0098x over previous
//
#include <hip/hip_runtime.h>

// input_tensor: (32, 64, 64, 64) fp32  -- d_in[0]
// pool_input:   (32, 128, 128, 64) fp32 -- d_in[1]
// out:          (32, 128, 128, 64) fp32
// POOL == STRIDES == (2,2): non-overlapping windows ->
//   out[b,h,w,c] = (pool[b,h,w,c] == window max) ? input[b,h/2,w/2,c] : 0
//
// R4: persistent software-pipelined kernel. Each thread processes 8 window
// tasks (1 window = 4 pool loads + 1 input load + 4 stores), prefetching
// iteration k+1's loads before iteration k's stores so reads and writes are
// continuously overlapped; wave launch/drain amortized 8x. Batch-major
// stride => next task's addresses are current + constant.

#define BB 32
#define HH 128
#define WW 128
#define CC 64
#define HO 64
#define WO 64
#define C4 (CC / 4)          // 16 float4 per (b,h,w)
#define WC4 (WW * C4)        // 2048 float4 per pool row

#define GRID 1024
#define BLOCK 256
#define THREADS (GRID * BLOCK)                 // 262,144
#define TASKS (BB * HO * WO * C4)              // 2,097,152
#define ITERS (TASKS / THREADS)                // 8
#define IN_STEP THREADS                        // input float4 step per iter (4 batches)
#define POOL_STEP (4 * HH * WW * C4)           // pool/out float4 step per iter (4 batches)

typedef float v4 __attribute__((ext_vector_type(4)));

__device__ __forceinline__ v4 vmax4(v4 a, v4 b) {
    v4 r;
    r.x = fmaxf(a.x, b.x); r.y = fmaxf(a.y, b.y);
    r.z = fmaxf(a.z, b.z); r.w = fmaxf(a.w, b.w);
    return r;
}

__device__ __forceinline__ v4 vsel(v4 p, v4 m, v4 v) {
    v4 r;
    r.x = (p.x == m.x) ? v.x : 0.0f;
    r.y = (p.y == m.y) ? v.y : 0.0f;
    r.z = (p.z == m.z) ? v.z : 0.0f;
    r.w = (p.w == m.w) ? v.w : 0.0f;
    return r;
}

__global__ __launch_bounds__(BLOCK) void unpool2d_kernel(
    const v4* __restrict__ input,  // (B,HO,WO,C4)
    const v4* __restrict__ pool,   // (B,H,W,C4)
    v4* __restrict__ out)          // (B,H,W,C4)
{
    int t = blockIdx.x * BLOCK + threadIdx.x;   // task id, iter 0 (b in 0..3)
    const int c4 = t & (C4 - 1);
    const int j  = (t >> 4) & (WO - 1);
    const int i  = (t >> 10) & (HO - 1);
    const int b  = t >> 16;

    int base = ((b * HH + 2 * i) * WW + 2 * j) * C4 + c4;
    int tin  = t;

    // Prologue: loads for iteration 0.
    v4 p00 = __builtin_nontemporal_load(&pool[base]);
    v4 p01 = __builtin_nontemporal_load(&pool[base + C4]);
    v4 p10 = __builtin_nontemporal_load(&pool[base + WC4]);
    v4 p11 = __builtin_nontemporal_load(&pool[base + WC4 + C4]);
    v4 v   = __builtin_nontemporal_load(&input[tin]);

#pragma unroll
    for (int it = 0; it < ITERS; ++it) {
        const int nbase = base + POOL_STEP;
        const int ntin  = tin + IN_STEP;
        v4 q00, q01, q10, q11, w;
        if (it + 1 < ITERS) {
            // Prefetch next iteration's 5 loads before this iteration's stores.
            q00 = __builtin_nontemporal_load(&pool[nbase]);
            q01 = __builtin_nontemporal_load(&pool[nbase + C4]);
            q10 = __builtin_nontemporal_load(&pool[nbase + WC4]);
            q11 = __builtin_nontemporal_load(&pool[nbase + WC4 + C4]);
            w   = __builtin_nontemporal_load(&input[ntin]);
        }

        const v4 m = vmax4(vmax4(p00, p01), vmax4(p10, p11));
        __builtin_nontemporal_store(vsel(p00, m, v), &out[base]);
        __builtin_nontemporal_store(vsel(p01, m, v), &out[base + C4]);
        __builtin_nontemporal_store(vsel(p10, m, v), &out[base + WC4]);
        __builtin_nontemporal_store(vsel(p11, m, v), &out[base + WC4 + C4]);

        base = nbase; tin = ntin;
        p00 = q00; p01 = q01; p10 = q10; p11 = q11; v = w;
    }
}

extern "C" void kernel_launch(void* const* d_in, const int* in_sizes, int n_in,
                              void* d_out, int out_size, void* d_ws, size_t ws_size,
                              hipStream_t stream) {
    const v4* input = (const v4*)d_in[0];
    const v4* pool  = (const v4*)d_in[1];
    v4* out = (v4*)d_out;

    unpool2d_kernel<<<GRID, BLOCK, 0, stream>>>(input, pool, out);
}